// Round 4
// baseline (7355.651 us; speedup 1.0000x reference)
//
#include <hip/hip_runtime.h>
#include <stdint.h>

typedef short bf16x8 __attribute__((ext_vector_type(8)));
typedef float f32x4 __attribute__((ext_vector_type(4)));
typedef unsigned int u32;
typedef unsigned short u16;
typedef unsigned long long u64;
typedef u32 u32x4 __attribute__((ext_vector_type(4)));

__device__ __forceinline__ float b2f(u16 h) {
  union { float f; u32 u; } x; x.u = ((u32)h) << 16; return x.f;
}
__device__ __forceinline__ u16 f2b(float f) {
  union { float f; u32 u; } x; x.f = f;
  u32 u = x.u;
  return (u16)((u + 0x7fffu + ((u >> 16) & 1u)) >> 16);
}
__device__ __forceinline__ float hsig(float z) {
  return fminf(fmaxf(__builtin_fmaf(0.2f, z, 0.5f), 0.f), 1.f);
}
__device__ __forceinline__ float tanh_fast(float x) {
  float xa = fminf(fmaxf(x, -15.f), 15.f);
  float e = __expf(2.f * xa);
  return (e - 1.f) / (e + 1.f);
}

// ---------------- fp32 -> bf16 convert (vectorized) ----------------
__global__ __launch_bounds__(256) void k_cvt(const float* __restrict__ in,
                                             u16* __restrict__ out, int n4) {
  int i = blockIdx.x * 256 + threadIdx.x;
  if (i >= n4) return;
  const float4 v = reinterpret_cast<const float4*>(in)[i];
  ushort4 o;
  o.x = f2b(v.x); o.y = f2b(v.y); o.z = f2b(v.z); o.w = f2b(v.w);
  reinterpret_cast<ushort4*>(out)[i] = o;
}

// ------------- fp32 [1024][4096] -> bf16 transposed [4096][1024] -------------
__global__ __launch_bounds__(256) void k_trcvt(const float* __restrict__ in,
                                               u16* __restrict__ out) {
  __shared__ float t[32][33];
  const int x = threadIdx.x & 31;
  const int y0 = threadIdx.x >> 5;
  const int c0 = blockIdx.x * 32;
  const int r0 = blockIdx.y * 32;
#pragma unroll
  for (int yy = 0; yy < 32; yy += 8)
    t[y0 + yy][x] = in[(size_t)(r0 + y0 + yy) * 4096 + c0 + x];
  __syncthreads();
#pragma unroll
  for (int yy = 0; yy < 32; yy += 8)
    out[(size_t)(c0 + y0 + yy) * 1024 + r0 + x] = f2b(t[x][y0 + yy]);
}

// ---------------- GEMM: xw = x(bf16 MxK) @ W (via W^T bf16 NxK) ----------------
__global__ __launch_bounds__(256) void k_gemm(const u16* __restrict__ A,
                                              const u16* __restrict__ BT,
                                              u16* __restrict__ C) {
  __shared__ u16 Al[128 * 32];
  __shared__ u16 Bl[128 * 32];
  const int tid = threadIdx.x;
  const int lane = tid & 63;
  const int w = tid >> 6;
  const int mbase = blockIdx.y * 128;
  const int nbase = blockIdx.x * 128;
  const int wr = (w >> 1) * 64, wc = (w & 1) * 64;
  const int g = lane >> 4, rr = lane & 15;
  f32x4 acc[4][4] = {};

  for (int kt = 0; kt < 32; ++kt) {
#pragma unroll
    for (int c = 0; c < 2; ++c) {
      int T = c * 256 + tid;
      int r = T >> 2;
      int ks = T & 3;
      int slot = ks ^ ((r >> 1) & 3);
      const u16* ga = A + (size_t)(mbase + r) * 1024 + kt * 32 + ks * 8;
      *reinterpret_cast<bf16x8*>(reinterpret_cast<char*>(Al) + r * 64 + slot * 16) =
          *reinterpret_cast<const bf16x8*>(ga);
      const u16* gb = BT + (size_t)(nbase + r) * 1024 + kt * 32 + ks * 8;
      *reinterpret_cast<bf16x8*>(reinterpret_cast<char*>(Bl) + r * 64 + slot * 16) =
          *reinterpret_cast<const bf16x8*>(gb);
    }
    __syncthreads();
    bf16x8 af[4], bfr[4];
#pragma unroll
    for (int mi = 0; mi < 4; ++mi) {
      int row = wr + mi * 16 + rr;
      int slot = g ^ ((row >> 1) & 3);
      af[mi] = *reinterpret_cast<const bf16x8*>(
          reinterpret_cast<const char*>(Al) + row * 64 + slot * 16);
      int coln = wc + mi * 16 + rr;
      int slotb = g ^ ((coln >> 1) & 3);
      bfr[mi] = *reinterpret_cast<const bf16x8*>(
          reinterpret_cast<const char*>(Bl) + coln * 64 + slotb * 16);
    }
#pragma unroll
    for (int mi = 0; mi < 4; ++mi)
#pragma unroll
      for (int ni = 0; ni < 4; ++ni)
        acc[mi][ni] = __builtin_amdgcn_mfma_f32_16x16x32_bf16(af[mi], bfr[ni],
                                                              acc[mi][ni], 0, 0, 0);
    __syncthreads();
  }
#pragma unroll
  for (int mi = 0; mi < 4; ++mi)
#pragma unroll
    for (int ni = 0; ni < 4; ++ni)
#pragma unroll
      for (int i = 0; i < 4; ++i) {
        int mrow = mbase + wr + mi * 16 + g * 4 + i;
        int col = nbase + wc + ni * 16 + rr;
        int orow = (mrow & 1023) * 32 + (mrow >> 10);
        C[(size_t)orow * 4096 + col] = f2b(acc[mi][ni][i]);
      }
}

// ---------------- zero h0 (parity0, 64KB) + flags (128) ----------------
__global__ __launch_bounds__(256) void k_zinit(u32* __restrict__ hb0,
                                               u32* __restrict__ flags) {
  int i = blockIdx.x * 256 + threadIdx.x;  // grid = 64*256 = 16384
  hb0[i] = 0;
  if (i < 128) flags[i] = 0;
}

#define LDS_LOAD(p, ord) \
  __hip_atomic_load((p), (ord), __HIP_MEMORY_SCOPE_WORKGROUP)
#define LDS_ADD(p) \
  __hip_atomic_fetch_add((p), 1u, __ATOMIC_ACQ_REL, __HIP_MEMORY_SCOPE_WORKGROUP)

// ---------------- persistent LSTM scan, 2-group pipelined ----------------
// 64 blocks x 768 threads (12 waves). Block owns units [bid*16, +16).
// Batch groups: A = batches 0-15, B = 16-31 — independent recurrence chains.
// Waves 0-7: MFMA (j = wv>>2 -> gate pair, kq = wv&3 -> K quarter) for BOTH
//   phases; waves 0-3 also gate-math A, waves 4-7 gate-math B.
// Waves 8,10: comm A (stage hlA halves, wave8 signals+polls flagsA).
// Waves 9,11: comm B (flagsB = flags+64).
// No __syncthreads in the loop: LDS seq flags (acquire/release) sequence
// everything; group B's global exchange hides under group A's compute & v.v.
__global__ __launch_bounds__(768, 1) void k_scan(const u16* __restrict__ rT,
                                                 const u16* __restrict__ xw,
                                                 u16* __restrict__ hbuf,
                                                 float* __restrict__ out,
                                                 u32* __restrict__ flags) {
  __shared__ char hlA[32768];            // h[b 0-15][1024] bf16, XOR-swizzled
  __shared__ char hlB[32768];            // h[b 16-31][...]
  __shared__ float zlA[4][4][16][17];    // [kq][gate][batch][unit]
  __shared__ float zlB[4][4][16][17];
  __shared__ u32 seq[8];  // 0 sqA,1 sqB,2 szA,3 szB,4 sgA,5 sgB

  const int tid = threadIdx.x, bid = blockIdx.x;
  const int lane = tid & 63, wv = tid >> 6;
  const int u0 = bid * 16;
  if (tid < 8) seq[tid] = 0;
  __syncthreads();  // only block-wide barrier in the kernel

  if (wv < 8) {
    // ================= MFMA + gate waves =================
    const int j = wv >> 2, kq = wv & 3;
    const int kg = lane >> 4, rr = lane & 15;
    const int swr = (rr & 7) << 4;
    bf16x8 Rf0[8], Rf1[8];
    {
      const u16* r0 = rT + (size_t)((2 * j) * 1024 + u0 + rr) * 1024 + kq * 256 + kg * 8;
      const u16* r1 = r0 + (size_t)1024 * 1024;
#pragma unroll
      for (int kt = 0; kt < 8; ++kt) {
        Rf0[kt] = *reinterpret_cast<const bf16x8*>(r0 + kt * 32);
        Rf1[kt] = *reinterpret_cast<const bf16x8*>(r1 + kt * 32);
      }
    }
    const bool gA = (wv < 4);
    const int gi = gA ? tid : (tid - 256);
    const int zb = gi >> 4;              // 0..15
    const int gb = (gA ? 0 : 16) + zb;   // absolute batch
    const int gu = gi & 15;              // unit within block
    const u16* xp = xw + (size_t)gb * 4096 + u0 + gu;
    const u16* xnext = xp + 131072;
    float* op = out + (size_t)gb * 1048576 + u0 + gu;
    u32 xq0, xq1, xq2, xq3;
    asm volatile("global_load_ushort %0, %1, off" : "=v"(xq0) : "v"(xp));
    asm volatile("global_load_ushort %0, %1, off" : "=v"(xq1) : "v"(xp + 1024));
    asm volatile("global_load_ushort %0, %1, off" : "=v"(xq2) : "v"(xp + 2048));
    asm volatile("global_load_ushort %0, %1, off" : "=v"(xq3) : "v"(xp + 3072));
    float creg = 0.f;

    for (int t = 0; t < 1024; ++t) {
      const u32 tgt2 = 2u * t + 2u, tgt8 = 8u * t + 8u;
      // ---- phase A MFMA ----
      while (LDS_LOAD(&seq[0], __ATOMIC_ACQUIRE) < tgt2) {}
      {
        f32x4 a0 = {0.f, 0.f, 0.f, 0.f}, a1 = {0.f, 0.f, 0.f, 0.f};
#pragma unroll
        for (int kt = 0; kt < 8; ++kt) {
          bf16x8 a = *reinterpret_cast<const bf16x8*>(
              hlA + rr * 2048 + ((kq * 512 + kt * 64 + kg * 16) ^ swr));
          a0 = __builtin_amdgcn_mfma_f32_16x16x32_bf16(a, Rf0[kt], a0, 0, 0, 0);
          a1 = __builtin_amdgcn_mfma_f32_16x16x32_bf16(a, Rf1[kt], a1, 0, 0, 0);
        }
#pragma unroll
        for (int i = 0; i < 4; ++i) {
          zlA[kq][2 * j][kg * 4 + i][rr] = a0[i];
          zlA[kq][2 * j + 1][kg * 4 + i][rr] = a1[i];
        }
      }
      if (lane == 0) LDS_ADD(&seq[2]);
      if (gA) {
        // ---- gate math, group A ----
        while (LDS_LOAD(&seq[2], __ATOMIC_ACQUIRE) < tgt8) {}
        asm volatile("s_waitcnt vmcnt(0)" ::: "memory");
        __builtin_amdgcn_sched_barrier(0);
        float zi = b2f((u16)xq0), zf = b2f((u16)xq1);
        float zc = b2f((u16)xq2), zo = b2f((u16)xq3);
#pragma unroll
        for (int q = 0; q < 4; ++q) {
          zi += zlA[q][0][zb][gu];
          zf += zlA[q][1][zb][gu];
          zc += zlA[q][2][zb][gu];
          zo += zlA[q][3][zb][gu];
        }
        creg = tanh_fast(hsig(zf) * creg + hsig(zi) * tanh_fast(zc));
        float hv = hsig(zo) * creg;
        if (t < 1023) {
          u32 hw = f2b(hv);
          u32 up = __shfl_down(hw, 1);
          if (!(gu & 1))
            __hip_atomic_store(
                reinterpret_cast<u32*>(hbuf + (((t + 1) & 1) << 15) + gb * 1024 +
                                       u0 + gu),
                hw | (up << 16), __ATOMIC_RELAXED, __HIP_MEMORY_SCOPE_AGENT);
          asm volatile("s_waitcnt vmcnt(0)" ::: "memory");  // h visible in L3
          if (lane == 0) LDS_ADD(&seq[4]);
        }
        *op = hv; op += 1024;
        if (t < 1023) {
          asm volatile("global_load_ushort %0, %1, off" : "=v"(xq0) : "v"(xnext));
          asm volatile("global_load_ushort %0, %1, off" : "=v"(xq1) : "v"(xnext + 1024));
          asm volatile("global_load_ushort %0, %1, off" : "=v"(xq2) : "v"(xnext + 2048));
          asm volatile("global_load_ushort %0, %1, off" : "=v"(xq3) : "v"(xnext + 3072));
          xnext += 131072;
        }
      }
      // ---- phase B MFMA ----
      while (LDS_LOAD(&seq[1], __ATOMIC_ACQUIRE) < tgt2) {}
      {
        f32x4 a0 = {0.f, 0.f, 0.f, 0.f}, a1 = {0.f, 0.f, 0.f, 0.f};
#pragma unroll
        for (int kt = 0; kt < 8; ++kt) {
          bf16x8 a = *reinterpret_cast<const bf16x8*>(
              hlB + rr * 2048 + ((kq * 512 + kt * 64 + kg * 16) ^ swr));
          a0 = __builtin_amdgcn_mfma_f32_16x16x32_bf16(a, Rf0[kt], a0, 0, 0, 0);
          a1 = __builtin_amdgcn_mfma_f32_16x16x32_bf16(a, Rf1[kt], a1, 0, 0, 0);
        }
#pragma unroll
        for (int i = 0; i < 4; ++i) {
          zlB[kq][2 * j][kg * 4 + i][rr] = a0[i];
          zlB[kq][2 * j + 1][kg * 4 + i][rr] = a1[i];
        }
      }
      if (lane == 0) LDS_ADD(&seq[3]);
      if (!gA) {
        // ---- gate math, group B ----
        while (LDS_LOAD(&seq[3], __ATOMIC_ACQUIRE) < tgt8) {}
        asm volatile("s_waitcnt vmcnt(0)" ::: "memory");
        __builtin_amdgcn_sched_barrier(0);
        float zi = b2f((u16)xq0), zf = b2f((u16)xq1);
        float zc = b2f((u16)xq2), zo = b2f((u16)xq3);
#pragma unroll
        for (int q = 0; q < 4; ++q) {
          zi += zlB[q][0][zb][gu];
          zf += zlB[q][1][zb][gu];
          zc += zlB[q][2][zb][gu];
          zo += zlB[q][3][zb][gu];
        }
        creg = tanh_fast(hsig(zf) * creg + hsig(zi) * tanh_fast(zc));
        float hv = hsig(zo) * creg;
        if (t < 1023) {
          u32 hw = f2b(hv);
          u32 up = __shfl_down(hw, 1);
          if (!(gu & 1))
            __hip_atomic_store(
                reinterpret_cast<u32*>(hbuf + (((t + 1) & 1) << 15) + gb * 1024 +
                                       u0 + gu),
                hw | (up << 16), __ATOMIC_RELAXED, __HIP_MEMORY_SCOPE_AGENT);
          asm volatile("s_waitcnt vmcnt(0)" ::: "memory");
          if (lane == 0) LDS_ADD(&seq[5]);
        }
        *op = hv; op += 1024;
        if (t < 1023) {
          asm volatile("global_load_ushort %0, %1, off" : "=v"(xq0) : "v"(xnext));
          asm volatile("global_load_ushort %0, %1, off" : "=v"(xq1) : "v"(xnext + 1024));
          asm volatile("global_load_ushort %0, %1, off" : "=v"(xq2) : "v"(xnext + 2048));
          asm volatile("global_load_ushort %0, %1, off" : "=v"(xq3) : "v"(xnext + 3072));
          xnext += 131072;
        }
      }
    }
  } else {
    // ================= comm waves =================
    const bool isA = ((wv & 1) == 0);   // 8,10 -> A; 9,11 -> B
    const int half = (wv >= 10);
    const int c0 = half * 16;
    char* hl = isA ? hlA : hlB;
    u32* sq = &seq[isA ? 0 : 1];
    u32* sg = &seq[isA ? 4 : 5];
    u32* flg = flags + (isA ? 0 : 64);
    const bool sig = (wv < 10);          // waves 8,9 signal
    const char* base0 = reinterpret_cast<const char*>(hbuf) + (isA ? 0 : 32768) +
                        lane * 16;
    const char* base1 = base0 + 65536;
    u32x4 sv[16];
    // pre-issue stage(t=0): parity 0 (zeroed by k_zinit)
#pragma unroll
    for (int i = 0; i < 16; ++i)
      asm volatile("global_load_dwordx4 %0, %1, off sc1"
                   : "=v"(sv[i]) : "v"(base0 + (c0 + i) * 1024));
    for (int t = 0; t < 1024; ++t) {
      asm volatile("s_waitcnt vmcnt(8)" ::: "memory");
#pragma unroll
      for (int i = 0; i < 8; ++i) {
        const int c = c0 + i;
        *reinterpret_cast<u32x4*>(
            hl + (c >> 1) * 2048 +
            ((((c & 1) << 10) + (lane << 4)) ^ (((c >> 1) & 7) << 4))) = sv[i];
      }
      asm volatile("s_waitcnt vmcnt(0)" ::: "memory");
#pragma unroll
      for (int i = 8; i < 16; ++i) {
        const int c = c0 + i;
        *reinterpret_cast<u32x4*>(
            hl + (c >> 1) * 2048 +
            ((((c & 1) << 10) + (lane << 4)) ^ (((c >> 1) & 7) << 4))) = sv[i];
      }
      if (lane == 0) LDS_ADD(sq);  // release: hl(t) ready
      if (t < 1023) {
        if (sig) {
          const u32 tgt4 = 4u * t + 4u;
          while (LDS_LOAD(sg, __ATOMIC_ACQUIRE) < tgt4) {}
          if (lane == 0)
            __hip_atomic_store(&flg[bid], (u32)(t + 1), __ATOMIC_RELAXED,
                               __HIP_MEMORY_SCOPE_AGENT);
        }
        while (__hip_atomic_load(&flg[lane], __ATOMIC_RELAXED,
                                 __HIP_MEMORY_SCOPE_AGENT) < (u32)(t + 1)) {}
        const char* nb = ((t + 1) & 1) ? base1 : base0;
#pragma unroll
        for (int i = 0; i < 16; ++i)
          asm volatile("global_load_dwordx4 %0, %1, off sc1"
                       : "=v"(sv[i]) : "v"(nb + (c0 + i) * 1024));
      }
    }
  }
}

extern "C" void kernel_launch(void* const* d_in, const int* in_sizes, int n_in,
                              void* d_out, int out_size, void* d_ws, size_t ws_size,
                              hipStream_t stream) {
  (void)in_sizes; (void)n_in; (void)out_size; (void)ws_size;
  const float* x = (const float*)d_in[0];
  const float* kern = (const float*)d_in[1];
  const float* rker = (const float*)d_in[2];
  float* out = (float*)d_out;
  char* ws = (char*)d_ws;

  u16* xbf = (u16*)ws;                                   // 67,108,864 B
  u16* kT = (u16*)(ws + 67108864);                       //  8,388,608 B
  u16* rT = (u16*)(ws + 67108864 + 8388608);             //  8,388,608 B
  u16* xw = (u16*)(ws + 83886080);                       // 268,435,456 B
  u16* hbuf = (u16*)(ws + 83886080 + 268435456);         //    131,072 B (2 par.)
  u32* flags = (u32*)(ws + 352321536 + 131072);          //        512 B

  k_cvt<<<32768, 256, 0, stream>>>(x, xbf, 8388608);
  k_trcvt<<<dim3(128, 32), 256, 0, stream>>>(kern, kT);
  k_trcvt<<<dim3(128, 32), 256, 0, stream>>>(rker, rT);
  k_gemm<<<dim3(32, 256), 256, 0, stream>>>(xbf, kT, xw);
  k_zinit<<<64, 256, 0, stream>>>((u32*)hbuf, flags);
  k_scan<<<64, 768, 0, stream>>>(rT, xw, hbuf, out, flags);
}

// Round 8
// 4254.705 us; speedup vs baseline: 1.7288x; 1.7288x over previous
//
#include <hip/hip_runtime.h>
#include <stdint.h>

typedef short bf16x8 __attribute__((ext_vector_type(8)));
typedef float f32x4 __attribute__((ext_vector_type(4)));
typedef unsigned int u32;
typedef unsigned short u16;
typedef u32 u32x4 __attribute__((ext_vector_type(4)));

__device__ __forceinline__ float b2f(u16 h) {
  union { float f; u32 u; } x; x.u = ((u32)h) << 16; return x.f;
}
__device__ __forceinline__ u16 f2b(float f) {
  union { float f; u32 u; } x; x.f = f;
  u32 u = x.u;
  return (u16)((u + 0x7fffu + ((u >> 16) & 1u)) >> 16);
}
__device__ __forceinline__ float hsig(float z) {
  return fminf(fmaxf(__builtin_fmaf(0.2f, z, 0.5f), 0.f), 1.f);
}
__device__ __forceinline__ float tanh_fast(float x) {
  float xa = fminf(fmaxf(x, -15.f), 15.f);
  float e = __expf(2.f * xa);
  return (e - 1.f) / (e + 1.f);
}

// ---------------- fp32 -> bf16 convert (vectorized) ----------------
__global__ __launch_bounds__(256) void k_cvt(const float* __restrict__ in,
                                             u16* __restrict__ out, int n4) {
  int i = blockIdx.x * 256 + threadIdx.x;
  if (i >= n4) return;
  const float4 v = reinterpret_cast<const float4*>(in)[i];
  ushort4 o;
  o.x = f2b(v.x); o.y = f2b(v.y); o.z = f2b(v.z); o.w = f2b(v.w);
  reinterpret_cast<ushort4*>(out)[i] = o;
}

// ------------- fp32 [1024][4096] -> bf16 transposed [4096][1024] -------------
__global__ __launch_bounds__(256) void k_trcvt(const float* __restrict__ in,
                                               u16* __restrict__ out) {
  __shared__ float t[32][33];
  const int x = threadIdx.x & 31;
  const int y0 = threadIdx.x >> 5;
  const int c0 = blockIdx.x * 32;
  const int r0 = blockIdx.y * 32;
#pragma unroll
  for (int yy = 0; yy < 32; yy += 8)
    t[y0 + yy][x] = in[(size_t)(r0 + y0 + yy) * 4096 + c0 + x];
  __syncthreads();
#pragma unroll
  for (int yy = 0; yy < 32; yy += 8)
    out[(size_t)(c0 + y0 + yy) * 1024 + r0 + x] = f2b(t[x][y0 + yy]);
}

// ---------------- GEMM: xw = x(bf16 MxK) @ W (via W^T bf16 NxK) ----------------
__global__ __launch_bounds__(256) void k_gemm(const u16* __restrict__ A,
                                              const u16* __restrict__ BT,
                                              u16* __restrict__ C) {
  __shared__ u16 Al[128 * 32];
  __shared__ u16 Bl[128 * 32];
  const int tid = threadIdx.x;
  const int lane = tid & 63;
  const int w = tid >> 6;
  const int mbase = blockIdx.y * 128;
  const int nbase = blockIdx.x * 128;
  const int wr = (w >> 1) * 64, wc = (w & 1) * 64;
  const int g = lane >> 4, rr = lane & 15;
  f32x4 acc[4][4] = {};

  for (int kt = 0; kt < 32; ++kt) {
#pragma unroll
    for (int c = 0; c < 2; ++c) {
      int T = c * 256 + tid;
      int r = T >> 2;
      int ks = T & 3;
      int slot = ks ^ ((r >> 1) & 3);
      const u16* ga = A + (size_t)(mbase + r) * 1024 + kt * 32 + ks * 8;
      *reinterpret_cast<bf16x8*>(reinterpret_cast<char*>(Al) + r * 64 + slot * 16) =
          *reinterpret_cast<const bf16x8*>(ga);
      const u16* gb = BT + (size_t)(nbase + r) * 1024 + kt * 32 + ks * 8;
      *reinterpret_cast<bf16x8*>(reinterpret_cast<char*>(Bl) + r * 64 + slot * 16) =
          *reinterpret_cast<const bf16x8*>(gb);
    }
    __syncthreads();
    bf16x8 af[4], bfr[4];
#pragma unroll
    for (int mi = 0; mi < 4; ++mi) {
      int row = wr + mi * 16 + rr;
      int slot = g ^ ((row >> 1) & 3);
      af[mi] = *reinterpret_cast<const bf16x8*>(
          reinterpret_cast<const char*>(Al) + row * 64 + slot * 16);
      int coln = wc + mi * 16 + rr;
      int slotb = g ^ ((coln >> 1) & 3);
      bfr[mi] = *reinterpret_cast<const bf16x8*>(
          reinterpret_cast<const char*>(Bl) + coln * 64 + slotb * 16);
    }
#pragma unroll
    for (int mi = 0; mi < 4; ++mi)
#pragma unroll
      for (int ni = 0; ni < 4; ++ni)
        acc[mi][ni] = __builtin_amdgcn_mfma_f32_16x16x32_bf16(af[mi], bfr[ni],
                                                              acc[mi][ni], 0, 0, 0);
    __syncthreads();
  }
#pragma unroll
  for (int mi = 0; mi < 4; ++mi)
#pragma unroll
    for (int ni = 0; ni < 4; ++ni)
#pragma unroll
      for (int i = 0; i < 4; ++i) {
        int mrow = mbase + wr + mi * 16 + g * 4 + i;
        int col = nbase + wc + ni * 16 + rr;
        int orow = (mrow & 1023) * 32 + (mrow >> 10);
        C[(size_t)orow * 4096 + col] = f2b(acc[mi][ni][i]);
      }
}

// ---------------- zero h0 (parity0, 64KB) + flags ----------------
__global__ __launch_bounds__(256) void k_zinit(u32* __restrict__ hb0,
                                               u32* __restrict__ flags) {
  int i = blockIdx.x * 256 + threadIdx.x;  // grid = 64*256 = 16384
  hb0[i] = 0;
  if (i < 128) flags[i] = 0;
}

// ---------------- persistent LSTM scan: 2-group software pipeline ------------
// 32 blocks x 512 threads (8 waves). Block owns units [bid*32, +32).
// Batch group A = b0-15, group B = b16-31: independent recurrences with
// independent flag arrays (flagsA = flags[0..31], flagsB = flags[32..63]).
// Per iteration t (4 unconditional __syncthreads):
//   S1: all waves MFMA A(t)            [hlA -> zlA]
//   S2: waves0-3 gates A(t)+hA(t+1)store+drain | waves4-7 poll flagsB>=t, stage hlB(t)
//   (sync; tid0 publishes flagsA=t+1)
//   S3: all waves MFMA B(t)            [hlB -> zlB]
//   S4: waves4-7 gates B(t)+hB store+drain | waves0-3 poll flagsA>=t+1, stage hlA(t+1)
//   (sync; tid256 publishes flagsB=t+1)
// Each group's flag round-trip overlaps the other group's MFMA+gate phases.
// Only proven primitives: agent atomics, sc1 staged loads, __syncthreads.
__global__ __launch_bounds__(512, 1) void k_scan(const u16* __restrict__ rT,
                                                 const u16* __restrict__ xw,
                                                 u16* __restrict__ hbuf,
                                                 float* __restrict__ out,
                                                 u32* __restrict__ flags) {
  __shared__ char hlA[32768];          // h[16 batches][1024 K] bf16, XOR-swizzled
  __shared__ char hlB[32768];
  __shared__ float zlA[4][2][16][33];  // [gate][kh][batch][unit(pad)]
  __shared__ float zlB[4][2][16][33];

  const int tid = threadIdx.x;
  const int bid = blockIdx.x;
  const int u0 = bid * 32;
  const int wv = tid >> 6;
  const int lane = tid & 63;
  const int j = wv >> 2;            // gate pair
  const int kh = (wv >> 1) & 1;     // K-half
  const int uh = wv & 1;            // unit-half
  const int kg = lane >> 4, rr = lane & 15;
  const int swr = (rr & 7) << 4;
  // staging mapping (within a 4-wave quad): 16 rows x 2048B, 8 dwordx4/lane
  const int sq = wv & 3;
  const int srow = sq * 4 + (lane >> 4);   // 0..15
  const int scol = (lane & 15) * 16;       // byte within row
  const int ssw = (srow & 7) << 4;
  // gate mapping (within a 4-wave group, 256 threads)
  const int gb = (tid & 255) >> 4;         // local batch 0..15
  const int gu = (tid & 15) * 2;           // unit pair
  const bool grpA = (wv < 4);
  const int bglob = (grpA ? 0 : 16) + gb;

  u32* flagsA = flags;
  u32* flagsB = flags + 32;

  // ---- R fragments: 2 gates x 16 kt (one K-half) ----
  bf16x8 Rf0[16], Rf1[16];
  {
    const u16* r0 = rT + (size_t)((2 * j) * 1024 + u0 + uh * 16 + rr) * 1024 +
                    kh * 512 + kg * 8;
    const u16* r1 = r0 + (size_t)1024 * 1024;
#pragma unroll
    for (int kt = 0; kt < 16; ++kt) {
      Rf0[kt] = *reinterpret_cast<const bf16x8*>(r0 + kt * 32);
      Rf1[kt] = *reinterpret_cast<const bf16x8*>(r1 + kt * 32);
    }
  }

  float c0 = 0.f, c1 = 0.f;
  float* outp = out + (size_t)bglob * 1048576 + u0 + gu;
  u32 xq0, xq1, xq2, xq3;
  {
    const u16* xb = xw + (size_t)bglob * 4096 + u0 + gu;  // t = 0
    asm volatile("global_load_dword %0, %1, off" : "=v"(xq0) : "v"(xb));
    asm volatile("global_load_dword %0, %1, off" : "=v"(xq1) : "v"(xb + 1024));
    asm volatile("global_load_dword %0, %1, off" : "=v"(xq2) : "v"(xb + 2048));
    asm volatile("global_load_dword %0, %1, off" : "=v"(xq3) : "v"(xb + 3072));
  }

  // ---- prologue: waves 0-3 stage hlA(0) (parity 0, zeroed by k_zinit) ----
  if (grpA) {
    const char* src = reinterpret_cast<const char*>(hbuf) + srow * 2048 + scol;
    u32x4 sv[8];
#pragma unroll
    for (int k = 0; k < 8; ++k)
      asm volatile("global_load_dwordx4 %0, %1, off sc1"
                   : "=v"(sv[k]) : "v"(src + k * 256));
    asm volatile("s_waitcnt vmcnt(0)" ::: "memory");
    __builtin_amdgcn_sched_barrier(0);
#pragma unroll
    for (int k = 0; k < 8; ++k)
      *reinterpret_cast<u32x4*>(hlA + srow * 2048 + ((scol + k * 256) ^ ssw)) = sv[k];
  }
  __syncthreads();

  for (int t = 0; t < 1024; ++t) {
    // ================= S1: MFMA A =================
    {
      f32x4 a0e = {0.f,0.f,0.f,0.f}, a0o = {0.f,0.f,0.f,0.f};
      f32x4 a1e = {0.f,0.f,0.f,0.f}, a1o = {0.f,0.f,0.f,0.f};
#pragma unroll
      for (int kt = 0; kt < 16; ++kt) {
        const int cb = kh * 1024 + kt * 64 + kg * 16;
        bf16x8 h = *reinterpret_cast<const bf16x8*>(hlA + rr * 2048 + (cb ^ swr));
        if (kt & 1) {
          a0o = __builtin_amdgcn_mfma_f32_16x16x32_bf16(h, Rf0[kt], a0o, 0, 0, 0);
          a1o = __builtin_amdgcn_mfma_f32_16x16x32_bf16(h, Rf1[kt], a1o, 0, 0, 0);
        } else {
          a0e = __builtin_amdgcn_mfma_f32_16x16x32_bf16(h, Rf0[kt], a0e, 0, 0, 0);
          a1e = __builtin_amdgcn_mfma_f32_16x16x32_bf16(h, Rf1[kt], a1e, 0, 0, 0);
        }
      }
#pragma unroll
      for (int i = 0; i < 4; ++i) {
        zlA[2 * j][kh][kg * 4 + i][uh * 16 + rr] = a0e[i] + a0o[i];
        zlA[2 * j + 1][kh][kg * 4 + i][uh * 16 + rr] = a1e[i] + a1o[i];
      }
    }
    __syncthreads();  // sync1: zlA ready; hlA consumption complete

    // ================= S2: gates A | poll+stage B =================
    if (grpA) {
      asm volatile("s_waitcnt vmcnt(0)" ::: "memory");  // xq ready
      __builtin_amdgcn_sched_barrier(0);
      float zi0 = zlA[0][0][gb][gu]   + zlA[0][1][gb][gu]   + b2f((u16)xq0);
      float zi1 = zlA[0][0][gb][gu+1] + zlA[0][1][gb][gu+1] + b2f((u16)(xq0 >> 16));
      float zf0 = zlA[1][0][gb][gu]   + zlA[1][1][gb][gu]   + b2f((u16)xq1);
      float zf1 = zlA[1][0][gb][gu+1] + zlA[1][1][gb][gu+1] + b2f((u16)(xq1 >> 16));
      float zc0 = zlA[2][0][gb][gu]   + zlA[2][1][gb][gu]   + b2f((u16)xq2);
      float zc1 = zlA[2][0][gb][gu+1] + zlA[2][1][gb][gu+1] + b2f((u16)(xq2 >> 16));
      float zo0 = zlA[3][0][gb][gu]   + zlA[3][1][gb][gu]   + b2f((u16)xq3);
      float zo1 = zlA[3][0][gb][gu+1] + zlA[3][1][gb][gu+1] + b2f((u16)(xq3 >> 16));
      c0 = tanh_fast(hsig(zf0) * c0 + hsig(zi0) * tanh_fast(zc0));  // ref carries tanh'd c
      c1 = tanh_fast(hsig(zf1) * c1 + hsig(zi1) * tanh_fast(zc1));
      float h0v = hsig(zo0) * c0, h1v = hsig(zo1) * c1;
      if (t < 1023) {
        __hip_atomic_store(
            reinterpret_cast<u32*>(hbuf + (size_t)((t + 1) & 1) * 32768 +
                                   gb * 1024 + u0 + gu),
            (u32)f2b(h0v) | ((u32)f2b(h1v) << 16), __ATOMIC_RELAXED,
            __HIP_MEMORY_SCOPE_AGENT);
        asm volatile("s_waitcnt vmcnt(0)" ::: "memory");  // hA drained
      }
      *reinterpret_cast<float2*>(outp) = make_float2(h0v, h1v);
      outp += 1024;
      if (t < 1023) {
        const u16* xb = xw + (size_t)((t + 1) * 32 + bglob) * 4096 + u0 + gu;
        asm volatile("global_load_dword %0, %1, off" : "=v"(xq0) : "v"(xb));
        asm volatile("global_load_dword %0, %1, off" : "=v"(xq1) : "v"(xb + 1024));
        asm volatile("global_load_dword %0, %1, off" : "=v"(xq2) : "v"(xb + 2048));
        asm volatile("global_load_dword %0, %1, off" : "=v"(xq3) : "v"(xb + 3072));
      }
    } else {
      // poll flagsB >= t (trivially true at t=0)
      u32 fv;
      do {
        fv = __hip_atomic_load(&flagsB[lane & 31], __ATOMIC_RELAXED,
                               __HIP_MEMORY_SCOPE_AGENT);
      } while (__any(fv < (u32)t));
      // stage hlB(t) from parity t&1, group offset 32768B
      const char* src = reinterpret_cast<const char*>(hbuf) +
                        (size_t)(t & 1) * 65536 + 32768 + srow * 2048 + scol;
      u32x4 sv[8];
#pragma unroll
      for (int k = 0; k < 8; ++k)
        asm volatile("global_load_dwordx4 %0, %1, off sc1"
                     : "=v"(sv[k]) : "v"(src + k * 256));
      asm volatile("s_waitcnt vmcnt(0)" ::: "memory");
      __builtin_amdgcn_sched_barrier(0);
#pragma unroll
      for (int k = 0; k < 8; ++k)
        *reinterpret_cast<u32x4*>(hlB + srow * 2048 + ((scol + k * 256) ^ ssw)) = sv[k];
    }
    __syncthreads();  // sync2: hlB ready; all hA stores drained
    if (t < 1023 && tid == 0)
      __hip_atomic_store(&flagsA[bid], (u32)(t + 1), __ATOMIC_RELAXED,
                         __HIP_MEMORY_SCOPE_AGENT);

    // ================= S3: MFMA B =================
    {
      f32x4 a0e = {0.f,0.f,0.f,0.f}, a0o = {0.f,0.f,0.f,0.f};
      f32x4 a1e = {0.f,0.f,0.f,0.f}, a1o = {0.f,0.f,0.f,0.f};
#pragma unroll
      for (int kt = 0; kt < 16; ++kt) {
        const int cb = kh * 1024 + kt * 64 + kg * 16;
        bf16x8 h = *reinterpret_cast<const bf16x8*>(hlB + rr * 2048 + (cb ^ swr));
        if (kt & 1) {
          a0o = __builtin_amdgcn_mfma_f32_16x16x32_bf16(h, Rf0[kt], a0o, 0, 0, 0);
          a1o = __builtin_amdgcn_mfma_f32_16x16x32_bf16(h, Rf1[kt], a1o, 0, 0, 0);
        } else {
          a0e = __builtin_amdgcn_mfma_f32_16x16x32_bf16(h, Rf0[kt], a0e, 0, 0, 0);
          a1e = __builtin_amdgcn_mfma_f32_16x16x32_bf16(h, Rf1[kt], a1e, 0, 0, 0);
        }
      }
#pragma unroll
      for (int i = 0; i < 4; ++i) {
        zlB[2 * j][kh][kg * 4 + i][uh * 16 + rr] = a0e[i] + a0o[i];
        zlB[2 * j + 1][kh][kg * 4 + i][uh * 16 + rr] = a1e[i] + a1o[i];
      }
    }
    __syncthreads();  // sync3: zlB ready; hlB consumption complete

    // ================= S4: gates B | poll+stage A(t+1) =================
    if (!grpA) {
      asm volatile("s_waitcnt vmcnt(0)" ::: "memory");
      __builtin_amdgcn_sched_barrier(0);
      float zi0 = zlB[0][0][gb][gu]   + zlB[0][1][gb][gu]   + b2f((u16)xq0);
      float zi1 = zlB[0][0][gb][gu+1] + zlB[0][1][gb][gu+1] + b2f((u16)(xq0 >> 16));
      float zf0 = zlB[1][0][gb][gu]   + zlB[1][1][gb][gu]   + b2f((u16)xq1);
      float zf1 = zlB[1][0][gb][gu+1] + zlB[1][1][gb][gu+1] + b2f((u16)(xq1 >> 16));
      float zc0 = zlB[2][0][gb][gu]   + zlB[2][1][gb][gu]   + b2f((u16)xq2);
      float zc1 = zlB[2][0][gb][gu+1] + zlB[2][1][gb][gu+1] + b2f((u16)(xq2 >> 16));
      float zo0 = zlB[3][0][gb][gu]   + zlB[3][1][gb][gu]   + b2f((u16)xq3);
      float zo1 = zlB[3][0][gb][gu+1] + zlB[3][1][gb][gu+1] + b2f((u16)(xq3 >> 16));
      c0 = tanh_fast(hsig(zf0) * c0 + hsig(zi0) * tanh_fast(zc0));
      c1 = tanh_fast(hsig(zf1) * c1 + hsig(zi1) * tanh_fast(zc1));
      float h0v = hsig(zo0) * c0, h1v = hsig(zo1) * c1;
      if (t < 1023) {
        __hip_atomic_store(
            reinterpret_cast<u32*>(hbuf + (size_t)((t + 1) & 1) * 32768 + 16384 +
                                   gb * 1024 + u0 + gu),
            (u32)f2b(h0v) | ((u32)f2b(h1v) << 16), __ATOMIC_RELAXED,
            __HIP_MEMORY_SCOPE_AGENT);
        asm volatile("s_waitcnt vmcnt(0)" ::: "memory");  // hB drained
      }
      *reinterpret_cast<float2*>(outp) = make_float2(h0v, h1v);
      outp += 1024;
      if (t < 1023) {
        const u16* xb = xw + (size_t)((t + 1) * 32 + bglob) * 4096 + u0 + gu;
        asm volatile("global_load_dword %0, %1, off" : "=v"(xq0) : "v"(xb));
        asm volatile("global_load_dword %0, %1, off" : "=v"(xq1) : "v"(xb + 1024));
        asm volatile("global_load_dword %0, %1, off" : "=v"(xq2) : "v"(xb + 2048));
        asm volatile("global_load_dword %0, %1, off" : "=v"(xq3) : "v"(xb + 3072));
      }
    } else if (t < 1023) {
      // poll flagsA >= t+1, stage hlA(t+1) from parity (t+1)&1
      u32 fv;
      do {
        fv = __hip_atomic_load(&flagsA[lane & 31], __ATOMIC_RELAXED,
                               __HIP_MEMORY_SCOPE_AGENT);
      } while (__any(fv < (u32)(t + 1)));
      const char* src = reinterpret_cast<const char*>(hbuf) +
                        (size_t)((t + 1) & 1) * 65536 + srow * 2048 + scol;
      u32x4 sv[8];
#pragma unroll
      for (int k = 0; k < 8; ++k)
        asm volatile("global_load_dwordx4 %0, %1, off sc1"
                     : "=v"(sv[k]) : "v"(src + k * 256));
      asm volatile("s_waitcnt vmcnt(0)" ::: "memory");
      __builtin_amdgcn_sched_barrier(0);
#pragma unroll
      for (int k = 0; k < 8; ++k)
        *reinterpret_cast<u32x4*>(hlA + srow * 2048 + ((scol + k * 256) ^ ssw)) = sv[k];
    }
    __syncthreads();  // sync4: hlA(t+1) ready; all hB stores drained
    if (t < 1023 && tid == 256)
      __hip_atomic_store(&flagsB[bid], (u32)(t + 1), __ATOMIC_RELAXED,
                         __HIP_MEMORY_SCOPE_AGENT);
  }
}

extern "C" void kernel_launch(void* const* d_in, const int* in_sizes, int n_in,
                              void* d_out, int out_size, void* d_ws, size_t ws_size,
                              hipStream_t stream) {
  (void)in_sizes; (void)n_in; (void)out_size; (void)ws_size;
  const float* x = (const float*)d_in[0];
  const float* kern = (const float*)d_in[1];
  const float* rker = (const float*)d_in[2];
  float* out = (float*)d_out;
  char* ws = (char*)d_ws;

  u16* xbf = (u16*)ws;                                   // 67,108,864 B
  u16* kT = (u16*)(ws + 67108864);                       //  8,388,608 B
  u16* rT = (u16*)(ws + 67108864 + 8388608);             //  8,388,608 B
  u16* xw = (u16*)(ws + 83886080);                       // 268,435,456 B
  u16* hbuf = (u16*)(ws + 83886080 + 268435456);         //    131,072 B (2 parity x 2 grp)
  u32* flags = (u32*)(ws + 352321536 + 131072);          //        512 B (A:32, B:32)

  k_cvt<<<32768, 256, 0, stream>>>(x, xbf, 8388608);
  k_trcvt<<<dim3(128, 32), 256, 0, stream>>>(kern, kT);
  k_trcvt<<<dim3(128, 32), 256, 0, stream>>>(rker, rT);
  k_gemm<<<dim3(32, 256), 256, 0, stream>>>(xbf, kT, xw);
  k_zinit<<<64, 256, 0, stream>>>((u32*)hbuf, flags);
  k_scan<<<32, 512, 0, stream>>>(rT, xw, hbuf, out, flags);
}